// Round 6
// baseline (547.312 us; speedup 1.0000x reference)
//
#include <hip/hip_runtime.h>
#include <hip/hip_bf16.h>

// B=4, S=8192 -> 32768 tokens; HID=1024; NH=DH=32.
// S1q: q=(query@Wq^T+bq)/32 -> bf16 @ dout_b[tok*2048 + n]
// S1k: k=(key@Wk^T+bk)      -> bf16 @ dout_b[tok*2048 + 1024 + n]
// S2 : per-token 32x32 scores + softmax over heads-t -> p (bf16 in d_ws if it
//      fits, else f32 in-place in d_out)
// S3 : v GEMM; epilogue out[idx] = p[idx] * (v+bv)
//
// GEMM: 128x128 tile, BK=64, 4 waves (64x64). bf16 LDS, row-major 128B rows
// with T2 XOR swizzle: addr(row,slot)=row*128+((slot^(row&7))<<4), slot=k/8.
//   global loads: 8 lanes x 32B contiguous per row  -> coalesced
//   ds_write_b128: 16-lane phase = 2 rows x 128B    -> conflict-free
//   ds_read_b128 : 16 lanes stride-128 xor'd        -> conflict-free
// Pipeline: rotation w/ single raw s_barrier per K-step, lgkmcnt drain only;
// global loads stay in flight across barriers (issued 1 phase before use).

typedef __attribute__((ext_vector_type(8))) short bf16x8;
typedef __attribute__((ext_vector_type(4))) float f32x4;

#define HID 1024

__device__ __forceinline__ unsigned short f2bf(float f) {
  unsigned int u = __builtin_bit_cast(unsigned int, f);
  u += 0x7FFFu + ((u >> 16) & 1u);  // RTNE
  return (unsigned short)(u >> 16);
}
__device__ __forceinline__ float bf2f(unsigned short h) {
  unsigned int u = (unsigned int)h << 16;
  return __builtin_bit_cast(float, u);
}

// 8 f32 (two f32x4) -> bf16x8 via v_cvt_pk_bf16_f32
__device__ __forceinline__ bf16x8 cvt8(f32x4 a, f32x4 b) {
  union { unsigned int u[4]; bf16x8 v; } r;
  asm("v_cvt_pk_bf16_f32 %0, %1, %2" : "=v"(r.u[0]) : "v"(a[0]), "v"(a[1]));
  asm("v_cvt_pk_bf16_f32 %0, %1, %2" : "=v"(r.u[1]) : "v"(a[2]), "v"(a[3]));
  asm("v_cvt_pk_bf16_f32 %0, %1, %2" : "=v"(r.u[2]) : "v"(b[0]), "v"(b[1]));
  asm("v_cvt_pk_bf16_f32 %0, %1, %2" : "=v"(r.u[3]) : "v"(b[2]), "v"(b[3]));
  return r.v;
}

// out[m,n] = sum_k X[m,k]*W[n,k] + b[n]
template<int MODE>
__global__ __launch_bounds__(256, 2)
void gemm_kernel(const float* __restrict__ X, const float* __restrict__ W,
                 const float* __restrict__ bias, void* outp,
                 const unsigned short* __restrict__ pbf, int use_ws) {
  // XCD-chunked bijective swizzle: 2048 blocks = 8 chunks x 256; n fastest.
  const int bid = blockIdx.x;
  const int L = (bid & 7) * 256 + (bid >> 3);
  const int m0 = (L >> 3) * 128;
  const int n0 = (L & 7) * 128;
  const int tid = threadIdx.x;
  const int lane = tid & 63;
  const int wid = tid >> 6;
  const int wm = (wid >> 1) << 6;
  const int wn = (wid & 1) << 6;
  const int lo = lane & 15, grp = lane >> 4;

  // per buffer: A bf16 [128][128B] @0 (16KB), B @16384. 2 buffers = 64KB.
  __shared__ __align__(16) unsigned char lds[2][32768];

  // staging: row = tid>>3 (+32*rr), slot = tid&7 (8 f32 = 32B global / 16B lds)
  const int srow = tid >> 3;             // 0..31
  const int sk8  = tid & 7;              // slot
  const float* Ag = X + (size_t)(m0 + srow) * HID + sk8 * 8;
  const float* Bg = W + (size_t)(n0 + srow) * HID + sk8 * 8;

  f32x4 la[4][2], lb[4][2];
  auto gload = [&](int k0) {
#pragma unroll
    for (int rr = 0; rr < 4; ++rr) {
      const float* ap = Ag + (size_t)(rr * 32) * HID + k0;
      const float* bp = Bg + (size_t)(rr * 32) * HID + k0;
      la[rr][0] = *(const f32x4*)(ap);
      la[rr][1] = *(const f32x4*)(ap + 4);
      lb[rr][0] = *(const f32x4*)(bp);
      lb[rr][1] = *(const f32x4*)(bp + 4);
    }
  };
  auto cvtwrite = [&](int b) {
#pragma unroll
    for (int rr = 0; rr < 4; ++rr) {
      const int row = srow + rr * 32;
      const int adr = row * 128 + ((sk8 ^ (row & 7)) << 4);
      *(bf16x8*)&lds[b][adr]         = cvt8(la[rr][0], la[rr][1]);
      *(bf16x8*)&lds[b][16384 + adr] = cvt8(lb[rr][0], lb[rr][1]);
    }
  };

  f32x4 acc[4][4] = {};
  auto compute = [&](int b) {
#pragma unroll
    for (int kk = 0; kk < 2; ++kk) {
      const int slot = kk * 4 + grp;
      bf16x8 af[4], bfm[4];
#pragma unroll
      for (int f = 0; f < 4; ++f) {
        const int ra = wm + f * 16 + lo;
        const int rb = wn + f * 16 + lo;
        af[f]  = *(const bf16x8*)&lds[b][ra * 128 + ((slot ^ (ra & 7)) << 4)];
        bfm[f] = *(const bf16x8*)&lds[b][16384 + rb * 128 + ((slot ^ (rb & 7)) << 4)];
      }
#pragma unroll
      for (int fm = 0; fm < 4; ++fm)
#pragma unroll
        for (int fn = 0; fn < 4; ++fn)
          acc[fm][fn] = __builtin_amdgcn_mfma_f32_16x16x32_bf16(
              af[fm], bfm[fn], acc[fm][fn], 0, 0, 0);
    }
  };

  // Prologue: tile0 staged, tile1 left in flight across the barrier.
  gload(0);
  cvtwrite(0);
  gload(64);
  __builtin_amdgcn_sched_barrier(0);
  asm volatile("s_waitcnt lgkmcnt(0)" ::: "memory");
  __builtin_amdgcn_s_barrier();
  __builtin_amdgcn_sched_barrier(0);

#pragma unroll 1
  for (int kt = 0; kt < 16; ++kt) {
    compute(kt & 1);                       // ds_read + MFMA on current buffer
    if (kt < 15) {
      cvtwrite((kt + 1) & 1);              // vmcnt wait lands here (1 phase late)
      if (kt < 14) gload((kt + 2) * 64);   // issue next; stays in flight
    }
    __builtin_amdgcn_sched_barrier(0);
    asm volatile("s_waitcnt lgkmcnt(0)" ::: "memory");  // ds ops drained only
    __builtin_amdgcn_s_barrier();          // raw: vmem loads NOT drained
    __builtin_amdgcn_sched_barrier(0);
  }

  // Epilogue. C layout: col=lane&15, row=(lane>>4)*4+j (m89-verified).
  unsigned char* eb = &lds[0][0];  // 32KB staging
  const unsigned char* ebc = eb;
  if (MODE == 2) {
    float* of = (float*)outp;
#pragma unroll
    for (int fm = 0; fm < 4; ++fm) {
      const int row = m0 + wm + fm * 16 + grp * 4;
#pragma unroll
      for (int fn = 0; fn < 4; ++fn) {
        const int col = n0 + wn + fn * 16 + lo;
        const float bc = bias[col];
#pragma unroll
        for (int j = 0; j < 4; ++j) {
          const size_t idx = (size_t)(row + j) * 1024 + col;
          const float p = use_ws ? bf2f(pbf[idx]) : of[idx];
          of[idx] = p * (acc[fm][fn][j] + bc);
        }
      }
    }
  } else {
    const float scale = (MODE == 0) ? 0.03125f : 1.0f;
#pragma unroll
    for (int fm = 0; fm < 4; ++fm) {
#pragma unroll
      for (int fn = 0; fn < 4; ++fn) {
        const int colL = wn + fn * 16 + lo;
        const float bc = bias[n0 + colL];
#pragma unroll
        for (int j = 0; j < 4; ++j) {
          const int rowL = wm + fm * 16 + grp * 4 + j;
          const int byte = rowL * 256 + ((colL * 2) ^ ((rowL & 7) << 5));
          *(unsigned short*)&eb[byte] = f2bf((acc[fm][fn][j] + bc) * scale);
        }
      }
    }
    __syncthreads();
    unsigned short* ob = (unsigned short*)outp;
    const int half = (MODE == 1) ? 1024 : 0;
#pragma unroll
    for (int p = 0; p < 8; ++p) {
      const int r = p * 16 + (tid >> 4);
      const int c0 = (tid & 15) * 8;
      const uint4 v = *(const uint4*)&ebc[r * 256 + ((c0 * 2) ^ ((r & 7) << 5))];
      *(uint4*)&ob[(size_t)(m0 + r) * 2048 + half + n0 + c0] = v;
    }
  }
}

// S2: one wave per token. 32x32 scores via 4 MFMA, softmax over t (cols).
// PMODE 0: write f32 p in-place over the token's q/k region in d_out.
// PMODE 1: write bf16 p to d_ws[tok*1024 + h*32 + t].
template<int PMODE>
__global__ __launch_bounds__(256)
void attn_kernel(float* __restrict__ dout, unsigned short* __restrict__ wsp) {
  const int wid = threadIdx.x >> 6;
  const int lane = threadIdx.x & 63;
  const int token = blockIdx.x * 4 + wid;
  const int lo = lane & 15, grp = lane >> 4;
  const unsigned short* qk = (const unsigned short*)dout + (size_t)token * 2048;
  const int base = lo * 32 + grp * 8;

  bf16x8 a0 = *(const bf16x8*)(qk + base);
  bf16x8 a1 = *(const bf16x8*)(qk + 512 + base);
  bf16x8 b0 = *(const bf16x8*)(qk + 1024 + base);
  bf16x8 b1 = *(const bf16x8*)(qk + 1536 + base);
  asm volatile("s_waitcnt vmcnt(0)" ::: "memory");  // before in-place overwrite

  const f32x4 z = {0.f, 0.f, 0.f, 0.f};
  f32x4 s[2][2];
  s[0][0] = __builtin_amdgcn_mfma_f32_16x16x32_bf16(a0, b0, z, 0, 0, 0);
  s[0][1] = __builtin_amdgcn_mfma_f32_16x16x32_bf16(a0, b1, z, 0, 0, 0);
  s[1][0] = __builtin_amdgcn_mfma_f32_16x16x32_bf16(a1, b0, z, 0, 0, 0);
  s[1][1] = __builtin_amdgcn_mfma_f32_16x16x32_bf16(a1, b1, z, 0, 0, 0);

  float* od = dout + (size_t)token * 1024;
  unsigned short* ob = wsp + (size_t)token * 1024;
#pragma unroll
  for (int rt = 0; rt < 2; ++rt) {
#pragma unroll
    for (int j = 0; j < 4; ++j) {
      const float v0 = s[rt][0][j], v1 = s[rt][1][j];
      float m = fmaxf(v0, v1);
#pragma unroll
      for (int msk = 1; msk < 16; msk <<= 1) m = fmaxf(m, __shfl_xor(m, msk, 64));
      const float e0 = __expf(v0 - m), e1 = __expf(v1 - m);
      float ssum = e0 + e1;
#pragma unroll
      for (int msk = 1; msk < 16; msk <<= 1) ssum += __shfl_xor(ssum, msk, 64);
      const float inv = 1.0f / ssum;
      const int h = rt * 16 + grp * 4 + j;
      if (PMODE == 0) {
        od[h * 32 + lo]      = e0 * inv;
        od[h * 32 + 16 + lo] = e1 * inv;
      } else {
        ob[h * 32 + lo]      = f2bf(e0 * inv);
        ob[h * 32 + 16 + lo] = f2bf(e1 * inv);
      }
    }
  }
}

extern "C" void kernel_launch(void* const* d_in, const int* in_sizes, int n_in,
                              void* d_out, int out_size, void* d_ws, size_t ws_size,
                              hipStream_t stream) {
  const float* query = (const float*)d_in[0];
  const float* key   = (const float*)d_in[1];
  const float* value = (const float*)d_in[2];
  const float* Wq    = (const float*)d_in[3];
  const float* bq    = (const float*)d_in[4];
  const float* Wk    = (const float*)d_in[5];
  const float* bk    = (const float*)d_in[6];
  const float* Wv    = (const float*)d_in[7];
  const float* bv    = (const float*)d_in[8];

  const int use_ws = (ws_size >= (size_t)32768 * 1024 * 2) ? 1 : 0;
  unsigned short* pbf = (unsigned short*)d_ws;

  gemm_kernel<0><<<dim3(2048), dim3(256), 0, stream>>>(query, Wq, bq, d_out, nullptr, 0);
  gemm_kernel<1><<<dim3(2048), dim3(256), 0, stream>>>(key,   Wk, bk, d_out, nullptr, 0);
  if (use_ws)
    attn_kernel<1><<<dim3(8192), dim3(256), 0, stream>>>((float*)d_out, pbf);
  else
    attn_kernel<0><<<dim3(8192), dim3(256), 0, stream>>>((float*)d_out, nullptr);
  gemm_kernel<2><<<dim3(2048), dim3(256), 0, stream>>>(value, Wv, bv, d_out, pbf, use_ws);
}

// Round 7
// 423.135 us; speedup vs baseline: 1.2935x; 1.2935x over previous
//
#include <hip/hip_runtime.h>
#include <hip/hip_bf16.h>

// B=4, S=8192 -> 32768 tokens; HID=1024; NH=DH=32.
// convw: Wq/Wk/Wv f32 -> bf16 in d_ws (2MB each)
// S1q: q=(query@Wq^T+bq)/32 -> bf16 @ dout_b[tok*2048 + n]
// S1k: k=(key@Wk^T+bk)      -> bf16 @ dout_b[tok*2048 + 1024 + n]
// S2 : per-token 32x32 scores + softmax over heads-t -> p bf16 @ d_ws[0:64MB)
// S3 : v GEMM; epilogue out[idx] = p[idx] * (v+bv)
//
// gemm_bf: 128x128 tile, BK=32, 4 waves (64x64). A: f32 staged DIRECTLY via
// global_load_lds w16 (no reg staging), cvt to bf16 at fragment read.
// B: bf16 (preconverted W). LDS dest linear (DMA rule), source granule16
// pre-XOR'd (A: s^(row&7), B: s^((row>>1)&3)); reads apply same XOR ->
// 2 lanes/bank everywhere (free). Counted vmcnt(6) pipeline: next tile's
// loads stay in flight across the raw s_barrier (never vmcnt(0) mid-loop).

typedef __attribute__((ext_vector_type(8))) short bf16x8;
typedef __attribute__((ext_vector_type(4))) float f32x4;

#define HID 1024

#define GLOAD_LDS16(gp, lp)                                                   \
  __builtin_amdgcn_global_load_lds(                                           \
      (const __attribute__((address_space(1))) void*)(gp),                    \
      (__attribute__((address_space(3))) void*)(lp), 16, 0, 0)

__device__ __forceinline__ unsigned short f2bf(float f) {
  unsigned int u = __builtin_bit_cast(unsigned int, f);
  u += 0x7FFFu + ((u >> 16) & 1u);  // RTNE
  return (unsigned short)(u >> 16);
}
__device__ __forceinline__ float bf2f(unsigned short h) {
  unsigned int u = (unsigned int)h << 16;
  return __builtin_bit_cast(float, u);
}

// 8 f32 (two f32x4) -> bf16x8 via v_cvt_pk_bf16_f32
__device__ __forceinline__ bf16x8 cvt8(f32x4 a, f32x4 b) {
  union { unsigned int u[4]; bf16x8 v; } r;
  asm("v_cvt_pk_bf16_f32 %0, %1, %2" : "=v"(r.u[0]) : "v"(a[0]), "v"(a[1]));
  asm("v_cvt_pk_bf16_f32 %0, %1, %2" : "=v"(r.u[1]) : "v"(a[2]), "v"(a[3]));
  asm("v_cvt_pk_bf16_f32 %0, %1, %2" : "=v"(r.u[2]) : "v"(b[0]), "v"(b[1]));
  asm("v_cvt_pk_bf16_f32 %0, %1, %2" : "=v"(r.u[3]) : "v"(b[2]), "v"(b[3]));
  return r.v;
}

// W f32 [1024][1024] -> bf16. grid 512 x 256, 8 elems/thread.
__global__ __launch_bounds__(256)
void convw_kernel(const float* __restrict__ src, unsigned short* __restrict__ dst) {
  const int i = blockIdx.x * 256 + threadIdx.x;
  const f32x4 a = ((const f32x4*)src)[i * 2];
  const f32x4 b = ((const f32x4*)src)[i * 2 + 1];
  ((bf16x8*)dst)[i] = cvt8(a, b);
}

// out[m,n] = sum_k X[m,k]*W[n,k] + b[n];  X f32, Wb bf16.
template<int MODE>
__global__ __launch_bounds__(256, 3)
void gemm_bf(const float* __restrict__ X, const unsigned short* __restrict__ Wb,
             const float* __restrict__ bias, void* outp,
             const unsigned short* __restrict__ pbf) {
  // XCD-chunked bijective swizzle: 2048 blocks = 8 chunks x 256; n fastest.
  const int bid = blockIdx.x;
  const int L = (bid & 7) * 256 + (bid >> 3);
  const int m0 = (L >> 3) * 128;
  const int n0 = (L & 7) * 128;
  const int tid = threadIdx.x;
  const int lane = tid & 63;
  const int wid = tid >> 6;
  const int wm = (wid >> 1) << 6;
  const int wn = (wid & 1) << 6;
  const int lo = lane & 15, grp = lane >> 4;

  // per buffer: A f32 [128][128B] @0 (16KB), B bf16 [128][64B] @16384 (8KB)
  __shared__ __align__(16) unsigned char lds[2][24576];

  // staging addresses (dest linear, source granule16 pre-XOR'd)
  size_t asrc[4]; unsigned int adst[4];
#pragma unroll
  for (int q = 0; q < 4; ++q) {
    const int g = q * 256 + tid;           // A granule, 8 per row
    const int row = g >> 3, s = g & 7;
    asrc[q] = (size_t)(m0 + row) * 4096 + (size_t)(((s ^ (row & 7)) << 4));
    adst[q] = g * 16;
  }
  size_t bsrc[2]; unsigned int bdst[2];
#pragma unroll
  for (int q = 0; q < 2; ++q) {
    const int g = q * 256 + tid;           // B granule, 4 per row
    const int row = g >> 2, s = g & 3;
    bsrc[q] = (size_t)(n0 + row) * 2048 + (size_t)(((s ^ ((row >> 1) & 3)) << 4));
    bdst[q] = 16384u + g * 16;
  }
  const char* Xc = (const char*)X;
  const char* Wc = (const char*)Wb;

  auto stage = [&](int b, int kt) {
    const size_t ka = (size_t)kt * 128;    // BK=32 f32 bytes
    const size_t kb = (size_t)kt * 64;     // BK=32 bf16 bytes
#pragma unroll
    for (int q = 0; q < 4; ++q) GLOAD_LDS16(Xc + asrc[q] + ka, &lds[b][adst[q]]);
#pragma unroll
    for (int q = 0; q < 2; ++q) GLOAD_LDS16(Wc + bsrc[q] + kb, &lds[b][bdst[q]]);
  };

  // fragment read offsets (per-thread constants)
  int aoff[4][2], boff[4];
#pragma unroll
  for (int f = 0; f < 4; ++f) {
    const int ra = wm + f * 16 + lo;
    aoff[f][0] = ra * 128 + ((((2 * grp)     ^ (ra & 7)) << 4));
    aoff[f][1] = ra * 128 + ((((2 * grp + 1) ^ (ra & 7)) << 4));
    const int rb = wn + f * 16 + lo;
    boff[f] = 16384 + rb * 64 + ((grp ^ ((rb >> 1) & 3)) << 4);
  }

  f32x4 acc[4][4] = {};
  auto compute = [&](int b) {
    bf16x8 af[4], bfm[4];
#pragma unroll
    for (int f = 0; f < 4; ++f) {
      const f32x4 a0 = *(const f32x4*)&lds[b][aoff[f][0]];
      const f32x4 a1 = *(const f32x4*)&lds[b][aoff[f][1]];
      af[f] = cvt8(a0, a1);
      bfm[f] = *(const bf16x8*)&lds[b][boff[f]];
    }
#pragma unroll
    for (int fm = 0; fm < 4; ++fm)
#pragma unroll
      for (int fn = 0; fn < 4; ++fn)
        acc[fm][fn] = __builtin_amdgcn_mfma_f32_16x16x32_bf16(
            af[fm], bfm[fn], acc[fm][fn], 0, 0, 0);
  };

  stage(0, 0);
#pragma unroll 1
  for (int kt = 0; kt < 32; ++kt) {
    if (kt < 31) {
      stage((kt + 1) & 1, kt + 1);         // 6 loads in flight across barrier
      __builtin_amdgcn_sched_barrier(0);
      asm volatile("s_waitcnt vmcnt(6)" ::: "memory");   // drain PREVIOUS 6 only
    } else {
      __builtin_amdgcn_sched_barrier(0);
      asm volatile("s_waitcnt vmcnt(0)" ::: "memory");
    }
    __builtin_amdgcn_s_barrier();
    __builtin_amdgcn_sched_barrier(0);
    compute(kt & 1);
    __builtin_amdgcn_sched_barrier(0);
    __builtin_amdgcn_s_barrier();          // readers done before next stage
    __builtin_amdgcn_sched_barrier(0);
  }

  // Epilogue. C layout: col=lane&15, row=(lane>>4)*4+j (m89-verified).
  unsigned char* eb = &lds[0][0];  // 32KB staging (of 48KB)
  const unsigned char* ebc = eb;
  if (MODE == 2) {
    float* of = (float*)outp;
#pragma unroll
    for (int fm = 0; fm < 4; ++fm) {
      const int row = m0 + wm + fm * 16 + grp * 4;
#pragma unroll
      for (int fn = 0; fn < 4; ++fn) {
        const int col = n0 + wn + fn * 16 + lo;
        const float bc = bias[col];
#pragma unroll
        for (int j = 0; j < 4; ++j) {
          const size_t idx = (size_t)(row + j) * 1024 + col;
          of[idx] = bf2f(pbf[idx]) * (acc[fm][fn][j] + bc);
        }
      }
    }
  } else {
    const float scale = (MODE == 0) ? 0.03125f : 1.0f;
#pragma unroll
    for (int fm = 0; fm < 4; ++fm) {
#pragma unroll
      for (int fn = 0; fn < 4; ++fn) {
        const int colL = wn + fn * 16 + lo;
        const float bc = bias[n0 + colL];
#pragma unroll
        for (int j = 0; j < 4; ++j) {
          const int rowL = wm + fm * 16 + grp * 4 + j;
          const int byte = rowL * 256 + ((colL * 2) ^ ((rowL & 7) << 5));
          *(unsigned short*)&eb[byte] = f2bf((acc[fm][fn][j] + bc) * scale);
        }
      }
    }
    __syncthreads();
    unsigned short* ob = (unsigned short*)outp;
    const int half = (MODE == 1) ? 1024 : 0;
#pragma unroll
    for (int p = 0; p < 8; ++p) {
      const int r = p * 16 + (tid >> 4);
      const int c0 = (tid & 15) * 8;
      const uint4 v = *(const uint4*)&ebc[r * 256 + ((c0 * 2) ^ ((r & 7) << 5))];
      *(uint4*)&ob[(size_t)(m0 + r) * 2048 + half + n0 + c0] = v;
    }
  }
}

// ---------- fallback GEMM (r6 path, used only if ws too small) ----------
template<int MODE>
__global__ __launch_bounds__(256, 2)
void gemm_fb(const float* __restrict__ X, const float* __restrict__ W,
             const float* __restrict__ bias, void* outp,
             const unsigned short* __restrict__ pbf, int use_ws) {
  const int bid = blockIdx.x;
  const int L = (bid & 7) * 256 + (bid >> 3);
  const int m0 = (L >> 3) * 128;
  const int n0 = (L & 7) * 128;
  const int tid = threadIdx.x;
  const int lane = tid & 63;
  const int wid = tid >> 6;
  const int wm = (wid >> 1) << 6;
  const int wn = (wid & 1) << 6;
  const int lo = lane & 15, grp = lane >> 4;
  __shared__ __align__(16) unsigned char lds[2][32768];
  const int srow = tid >> 3;
  const int sk8  = tid & 7;
  const float* Ag = X + (size_t)(m0 + srow) * HID + sk8 * 8;
  const float* Bg = W + (size_t)(n0 + srow) * HID + sk8 * 8;
  f32x4 la[4][2], lb[4][2];
  auto gload = [&](int k0) {
#pragma unroll
    for (int rr = 0; rr < 4; ++rr) {
      const float* ap = Ag + (size_t)(rr * 32) * HID + k0;
      const float* bp = Bg + (size_t)(rr * 32) * HID + k0;
      la[rr][0] = *(const f32x4*)(ap); la[rr][1] = *(const f32x4*)(ap + 4);
      lb[rr][0] = *(const f32x4*)(bp); lb[rr][1] = *(const f32x4*)(bp + 4);
    }
  };
  auto cvtwrite = [&](int b) {
#pragma unroll
    for (int rr = 0; rr < 4; ++rr) {
      const int row = srow + rr * 32;
      const int adr = row * 128 + ((sk8 ^ (row & 7)) << 4);
      *(bf16x8*)&lds[b][adr]         = cvt8(la[rr][0], la[rr][1]);
      *(bf16x8*)&lds[b][16384 + adr] = cvt8(lb[rr][0], lb[rr][1]);
    }
  };
  f32x4 acc[4][4] = {};
  auto compute = [&](int b) {
#pragma unroll
    for (int kk = 0; kk < 2; ++kk) {
      const int slot = kk * 4 + grp;
      bf16x8 af[4], bfm[4];
#pragma unroll
      for (int f = 0; f < 4; ++f) {
        const int ra = wm + f * 16 + lo;
        const int rb = wn + f * 16 + lo;
        af[f]  = *(const bf16x8*)&lds[b][ra * 128 + ((slot ^ (ra & 7)) << 4)];
        bfm[f] = *(const bf16x8*)&lds[b][16384 + rb * 128 + ((slot ^ (rb & 7)) << 4)];
      }
#pragma unroll
      for (int fm = 0; fm < 4; ++fm)
#pragma unroll
        for (int fn = 0; fn < 4; ++fn)
          acc[fm][fn] = __builtin_amdgcn_mfma_f32_16x16x32_bf16(
              af[fm], bfm[fn], acc[fm][fn], 0, 0, 0);
    }
  };
  gload(0); cvtwrite(0); gload(64);
  __builtin_amdgcn_sched_barrier(0);
  asm volatile("s_waitcnt lgkmcnt(0)" ::: "memory");
  __builtin_amdgcn_s_barrier();
  __builtin_amdgcn_sched_barrier(0);
#pragma unroll 1
  for (int kt = 0; kt < 16; ++kt) {
    compute(kt & 1);
    if (kt < 15) {
      cvtwrite((kt + 1) & 1);
      if (kt < 14) gload((kt + 2) * 64);
    }
    __builtin_amdgcn_sched_barrier(0);
    asm volatile("s_waitcnt lgkmcnt(0)" ::: "memory");
    __builtin_amdgcn_s_barrier();
    __builtin_amdgcn_sched_barrier(0);
  }
  unsigned char* eb = &lds[0][0];
  const unsigned char* ebc = eb;
  if (MODE == 2) {
    float* of = (float*)outp;
#pragma unroll
    for (int fm = 0; fm < 4; ++fm) {
      const int row = m0 + wm + fm * 16 + grp * 4;
#pragma unroll
      for (int fn = 0; fn < 4; ++fn) {
        const int col = n0 + wn + fn * 16 + lo;
        const float bc = bias[col];
#pragma unroll
        for (int j = 0; j < 4; ++j) {
          const size_t idx = (size_t)(row + j) * 1024 + col;
          const float p = use_ws ? bf2f(pbf[idx]) : of[idx];
          of[idx] = p * (acc[fm][fn][j] + bc);
        }
      }
    }
  } else {
    const float scale = (MODE == 0) ? 0.03125f : 1.0f;
#pragma unroll
    for (int fm = 0; fm < 4; ++fm) {
#pragma unroll
      for (int fn = 0; fn < 4; ++fn) {
        const int colL = wn + fn * 16 + lo;
        const float bc = bias[n0 + colL];
#pragma unroll
        for (int j = 0; j < 4; ++j) {
          const int rowL = wm + fm * 16 + grp * 4 + j;
          const int byte = rowL * 256 + ((colL * 2) ^ ((rowL & 7) << 5));
          *(unsigned short*)&eb[byte] = f2bf((acc[fm][fn][j] + bc) * scale);
        }
      }
    }
    __syncthreads();
    unsigned short* ob = (unsigned short*)outp;
    const int half = (MODE == 1) ? 1024 : 0;
#pragma unroll
    for (int p = 0; p < 8; ++p) {
      const int r = p * 16 + (tid >> 4);
      const int c0 = (tid & 15) * 8;
      const uint4 v = *(const uint4*)&ebc[r * 256 + ((c0 * 2) ^ ((r & 7) << 5))];
      *(uint4*)&ob[(size_t)(m0 + r) * 2048 + half + n0 + c0] = v;
    }
  }
}

// S2: one wave per token. 32x32 scores via 4 MFMA, softmax over t (cols).
template<int PMODE>
__global__ __launch_bounds__(256)
void attn_kernel(float* __restrict__ dout, unsigned short* __restrict__ wsp) {
  const int wid = threadIdx.x >> 6;
  const int lane = threadIdx.x & 63;
  const int token = blockIdx.x * 4 + wid;
  const int lo = lane & 15, grp = lane >> 4;
  const unsigned short* qk = (const unsigned short*)dout + (size_t)token * 2048;
  const int base = lo * 32 + grp * 8;

  bf16x8 a0 = *(const bf16x8*)(qk + base);
  bf16x8 a1 = *(const bf16x8*)(qk + 512 + base);
  bf16x8 b0 = *(const bf16x8*)(qk + 1024 + base);
  bf16x8 b1 = *(const bf16x8*)(qk + 1536 + base);
  asm volatile("s_waitcnt vmcnt(0)" ::: "memory");

  const f32x4 z = {0.f, 0.f, 0.f, 0.f};
  f32x4 s[2][2];
  s[0][0] = __builtin_amdgcn_mfma_f32_16x16x32_bf16(a0, b0, z, 0, 0, 0);
  s[0][1] = __builtin_amdgcn_mfma_f32_16x16x32_bf16(a0, b1, z, 0, 0, 0);
  s[1][0] = __builtin_amdgcn_mfma_f32_16x16x32_bf16(a1, b0, z, 0, 0, 0);
  s[1][1] = __builtin_amdgcn_mfma_f32_16x16x32_bf16(a1, b1, z, 0, 0, 0);

  float* od = dout + (size_t)token * 1024;
  unsigned short* ob = wsp + (size_t)token * 1024;
#pragma unroll
  for (int rt = 0; rt < 2; ++rt) {
#pragma unroll
    for (int j = 0; j < 4; ++j) {
      const float v0 = s[rt][0][j], v1 = s[rt][1][j];
      float m = fmaxf(v0, v1);
#pragma unroll
      for (int msk = 1; msk < 16; msk <<= 1) m = fmaxf(m, __shfl_xor(m, msk, 64));
      const float e0 = __expf(v0 - m), e1 = __expf(v1 - m);
      float ssum = e0 + e1;
#pragma unroll
      for (int msk = 1; msk < 16; msk <<= 1) ssum += __shfl_xor(ssum, msk, 64);
      const float inv = 1.0f / ssum;
      const int h = rt * 16 + grp * 4 + j;
      if (PMODE == 0) {
        od[h * 32 + lo]      = e0 * inv;
        od[h * 32 + 16 + lo] = e1 * inv;
      } else {
        ob[h * 32 + lo]      = f2bf(e0 * inv);
        ob[h * 32 + 16 + lo] = f2bf(e1 * inv);
      }
    }
  }
}

extern "C" void kernel_launch(void* const* d_in, const int* in_sizes, int n_in,
                              void* d_out, int out_size, void* d_ws, size_t ws_size,
                              hipStream_t stream) {
  const float* query = (const float*)d_in[0];
  const float* key   = (const float*)d_in[1];
  const float* value = (const float*)d_in[2];
  const float* Wq    = (const float*)d_in[3];
  const float* bq    = (const float*)d_in[4];
  const float* Wk    = (const float*)d_in[5];
  const float* bk    = (const float*)d_in[6];
  const float* Wv    = (const float*)d_in[7];
  const float* bv    = (const float*)d_in[8];

  const size_t P_BYTES = (size_t)32768 * 1024 * 2;   // 64 MB (p bf16)
  const size_t W_BYTES = (size_t)1024 * 1024 * 2;    // 2 MB per W
  unsigned short* pbf = (unsigned short*)d_ws;
  unsigned short* Wqb = (unsigned short*)((char*)d_ws + P_BYTES);
  unsigned short* Wkb = Wqb + (W_BYTES / 2);
  unsigned short* Wvb = Wkb + (W_BYTES / 2);

  if (ws_size >= P_BYTES + 3 * W_BYTES) {
    convw_kernel<<<dim3(512), dim3(256), 0, stream>>>(Wq, Wqb);
    convw_kernel<<<dim3(512), dim3(256), 0, stream>>>(Wk, Wkb);
    convw_kernel<<<dim3(512), dim3(256), 0, stream>>>(Wv, Wvb);
    gemm_bf<0><<<dim3(2048), dim3(256), 0, stream>>>(query, Wqb, bq, d_out, pbf);
    gemm_bf<1><<<dim3(2048), dim3(256), 0, stream>>>(key,   Wkb, bk, d_out, pbf);
    attn_kernel<1><<<dim3(8192), dim3(256), 0, stream>>>((float*)d_out, pbf);
    gemm_bf<2><<<dim3(2048), dim3(256), 0, stream>>>(value, Wvb, bv, d_out, pbf);
  } else {
    const int use_ws = (ws_size >= P_BYTES) ? 1 : 0;
    gemm_fb<0><<<dim3(2048), dim3(256), 0, stream>>>(query, Wq, bq, d_out, nullptr, 0);
    gemm_fb<1><<<dim3(2048), dim3(256), 0, stream>>>(key,   Wk, bk, d_out, nullptr, 0);
    if (use_ws)
      attn_kernel<1><<<dim3(8192), dim3(256), 0, stream>>>((float*)d_out, pbf);
    else
      attn_kernel<0><<<dim3(8192), dim3(256), 0, stream>>>((float*)d_out, nullptr);
    gemm_fb<2><<<dim3(2048), dim3(256), 0, stream>>>(value, Wv, bv, d_out, pbf, use_ws);
  }
}